// Round 6
// baseline (165.051 us; speedup 1.0000x reference)
//
#include <hip/hip_runtime.h>

// Problem constants (from reference): B=4, N=100000, C=500, H=W=512.
#define B_DIM 4
#define N_DIM 100000
#define C_DIM 500
#define TOTAL_ROWS (B_DIM * N_DIM)   // 400000
#define NBATCH (TOTAL_ROWS / 2)      // 200000 (2 rows per batch)
#define IMG_W 512.0f
#define IMG_H 512.0f

typedef float floatx4 __attribute__((ext_vector_type(4)));

// 500 floats = 125 float4/row. Lane l covers vec l (chunk 0) and vec
// min(l+64,124) (chunk 1; lanes 61-63 duplicate vec 124 with its TRUE index,
// so the lowest-lane ballot tie-break still returns the first occurrence).
//
// R6 changes vs R5:
//  - PLAIN (cached) loads, not nontemporal: 2000B rows are not sector-aligned;
//    boundary 128B sectors are shared with the adjacent batch and must be
//    served from L2, not refetched from HBM.
//  - XCD-contiguous wave remap: grid=2048, 8 XCDs, 256 blocks/XCD (exact ->
//    bijective). All sharers of a cls boundary sector / partial output line
//    sit on ONE XCD's L2 -> full-line writebacks, no cross-XCD refetch.

__device__ __forceinline__ void scan4(floatx4 q, int i0, float& best, int& bidx) {
    if (q.x > best) { best = q.x; bidx = i0;     }
    if (q.y > best) { best = q.y; bidx = i0 + 1; }
    if (q.z > best) { best = q.z; bidx = i0 + 2; }
    if (q.w > best) { best = q.w; bidx = i0 + 3; }
}

struct Stage {
    floatx4 q00, q10, q01, q11;  // cls: (row0,row1) x (chunk0,chunk1)
    floatx4 a, r;                // anchors / regressions for row base+lidx
};

__device__ __forceinline__ Stage load_stage(
    const float* __restrict__ cls, const float* __restrict__ anchors,
    const float* __restrict__ reg, int batch, int lane, int v1, int lidx)
{
    Stage s;
    const int base = batch * 2;
    const floatx4* p0 = (const floatx4*)(cls + (size_t)base * C_DIM);
    const floatx4* p1 = (const floatx4*)(cls + (size_t)(base + 1) * C_DIM);
    s.q00 = p0[lane];
    s.q10 = p1[lane];
    s.q01 = p0[v1];
    s.q11 = p1[v1];
    const int rw = base + lidx;
    s.a = *(const floatx4*)(anchors + (size_t)(rw % N_DIM) * 4);
    s.r = *(const floatx4*)(reg + (size_t)rw * 4);
    return s;
}

__global__ __launch_bounds__(256) void InferenceTransform_66202625900988_kernel(
    const float* __restrict__ cls,       // [B,N,C]
    const float* __restrict__ reg,       // [B,N,4]
    const float* __restrict__ anchors,   // [1,N,4]
    const float* __restrict__ thresh_p,  // [1]
    const float* __restrict__ rfac,      // [4]
    float* __restrict__ out)             // boxes[B*N*4] | cls[B*N] | scores[B*N] | mask[B*N]
{
    const int lane          = threadIdx.x & 63;
    const int waveInBlock   = threadIdx.x >> 6;
    const int wavesPerBlock = blockDim.x >> 6;
    const int nWaves        = gridDim.x * wavesPerBlock;

    // XCD-contiguous remap (MI355X: 8 XCDs, round-robin block dispatch).
    // grid=2048 -> 256 blocks/XCD exactly; bijection on [0, 2048).
    const int xcd    = blockIdx.x & 7;
    const int slot   = blockIdx.x >> 3;
    const int waveId = (xcd * (gridDim.x >> 3) + slot) * wavesPerBlock + waveInBlock;

    const int v1   = (lane + 64 < C_DIM / 4) ? (lane + 64) : (C_DIM / 4 - 1);
    const int lidx = (lane < 2) ? lane : 1;   // lanes >=2 replicate lane 1

    const float thresh = thresh_p[0];
    const float rf0 = rfac[0], rf1 = rfac[1], rf2 = rfac[2], rf3 = rfac[3];

    float*       outBoxes = out;
    float*       outCls   = out + (size_t)TOTAL_ROWS * 4;
    float*       outScore = outCls + (size_t)TOTAL_ROWS;
    float*       outMask  = outScore + (size_t)TOTAL_ROWS;

    int batch = waveId;   // 8192 waves <= 200000 batches: all waves have work
    Stage cur = load_stage(cls, anchors, reg, batch, lane, v1, lidx);

    while (true) {
        const int nb = batch + nWaves;
        // Clamped (never branched) prefetch: final iteration prefetches batch
        // 0 -- all waves share those 4 KB, L2 absorbs it.
        const int pb = (nb < NBATCH) ? nb : 0;
        Stage nxt = load_stage(cls, anchors, reg, pb, lane, v1, lidx);

        // ---- process current batch (rows base, base+1) ----
        const int base = batch * 2;
        float loc0 = -1.0f, loc1 = -1.0f;
        int   bidx0 = 0,    bidx1 = 0;
        scan4(cur.q00, 4 * lane, loc0, bidx0);
        scan4(cur.q10, 4 * lane, loc1, bidx1);
        scan4(cur.q01, 4 * v1,   loc0, bidx0);   // dup lanes carry true idx
        scan4(cur.q11, 4 * v1,   loc1, bidx1);

        float w0 = loc0, w1 = loc1;
        #pragma unroll
        for (int off = 32; off > 0; off >>= 1) {
            w0 = fmaxf(w0, __shfl_xor(w0, off, 64));
            w1 = fmaxf(w1, __shfl_xor(w1, off, 64));
        }

        // Argmax: prefer chunk-0 (idx<256) candidates; idx monotone (non-
        // decreasing) in lane within a chunk -> lowest set lane = first idx.
        unsigned long long c0a = __ballot(loc0 == w0 && bidx0 < 256);
        unsigned long long c0  = c0a ? c0a : __ballot(loc0 == w0);
        unsigned long long c1a = __ballot(loc1 == w1 && bidx1 < 256);
        unsigned long long c1  = c1a ? c1a : __ballot(loc1 == w1);
        int idx0 = __shfl(bidx0, (int)__builtin_ctzll(c0), 64);
        int idx1 = __shfl(bidx1, (int)__builtin_ctzll(c1), 64);

        // ---- epilogue on ALL lanes (lanes>=2 exactly replicate lane 1;
        // duplicate-address stores coalesce) ----
        {
            const int   row  = base + lidx;
            const float best = lidx ? w1 : w0;
            const int   bidx = lidx ? idx1 : idx0;

            float width  = cur.a.z - cur.a.x;
            float height = cur.a.w - cur.a.y;
            float ctrx   = cur.a.x + 0.5f * width;
            float ctry   = cur.a.y + 0.5f * height;

            float px = ctrx + (cur.r.x * rf0) * width;
            float py = ctry + (cur.r.y * rf1) * height;
            float pw = __expf(cur.r.z * rf2) * width;
            float ph = __expf(cur.r.w * rf3) * height;

            float x1 = fminf(fmaxf(px - 0.5f * pw, 0.0f), IMG_W);
            float y1 = fminf(fmaxf(py - 0.5f * ph, 0.0f), IMG_H);
            float x2 = fminf(fmaxf(px + 0.5f * pw, 0.0f), IMG_W);
            float y2 = fminf(fmaxf(py + 0.5f * ph, 0.0f), IMG_H);

            const float m = (best > thresh) ? 1.0f : 0.0f;

            floatx4 box;
            box.x = x1 * m; box.y = y1 * m; box.z = x2 * m; box.w = y2 * m;
            *(floatx4*)(outBoxes + (size_t)row * 4) = box;
            outCls[row]   = m != 0.0f ? (float)bidx : 0.0f;
            outScore[row] = best * m;
            outMask[row]  = m;
        }

        if (nb >= NBATCH) break;
        batch = nb;
        cur = nxt;
    }
}

extern "C" void kernel_launch(void* const* d_in, const int* in_sizes, int n_in,
                              void* d_out, int out_size, void* d_ws, size_t ws_size,
                              hipStream_t stream) {
    // Input order per setup_inputs(): imgs, classifications, regressions,
    // anchors, cls_thresh, regress_factor.
    const float* cls     = (const float*)d_in[1];
    const float* reg     = (const float*)d_in[2];
    const float* anchors = (const float*)d_in[3];
    const float* thresh  = (const float*)d_in[4];
    const float* rfac    = (const float*)d_in[5];
    float* out = (float*)d_out;

    const int block = 256;   // 4 waves/block
    const int grid  = 2048;  // 8192 waves; 256 blocks per XCD (exact)

    InferenceTransform_66202625900988_kernel<<<grid, block, 0, stream>>>(
        cls, reg, anchors, thresh, rfac, out);
}

// Round 7
// 146.364 us; speedup vs baseline: 1.1277x; 1.1277x over previous
//
#include <hip/hip_runtime.h>

// Problem constants (from reference): B=4, N=100000, C=500, H=W=512.
#define B_DIM 4
#define N_DIM 100000
#define C_DIM 500
#define TOTAL_ROWS (B_DIM * N_DIM)   // 400000
#define NBATCH (TOTAL_ROWS / 2)      // 200000 (2 rows per batch)
#define IMG_W 512.0f
#define IMG_H 512.0f

typedef float floatx4 __attribute__((ext_vector_type(4)));

// 500 floats = 125 float4/row. Lane l covers vec l (chunk 0) and vec
// min(l+64,124) (chunk 1; lanes 61-63 duplicate vec 124 with its TRUE index,
// so the lowest-lane ballot tie-break still returns the first occurrence).
//
// R7 = R5 (nontemporal cls loads restored -- keeps the 800MB zero-reuse
// stream OUT of L2/L3 so partially-merged output lines aren't evicted)
//    + R6's XCD-contiguous wave remap ONLY (clean A/B vs R5).

__device__ __forceinline__ void scan4(floatx4 q, int i0, float& best, int& bidx) {
    if (q.x > best) { best = q.x; bidx = i0;     }
    if (q.y > best) { best = q.y; bidx = i0 + 1; }
    if (q.z > best) { best = q.z; bidx = i0 + 2; }
    if (q.w > best) { best = q.w; bidx = i0 + 3; }
}

struct Stage {
    floatx4 q00, q10, q01, q11;  // cls: (row0,row1) x (chunk0,chunk1)
    floatx4 a, r;                // anchors / regressions for row base+lidx
};

__device__ __forceinline__ Stage load_stage(
    const float* __restrict__ cls, const float* __restrict__ anchors,
    const float* __restrict__ reg, int batch, int lane, int v1, int lidx)
{
    Stage s;
    const int base = batch * 2;
    const floatx4* p0 = (const floatx4*)(cls + (size_t)base * C_DIM);
    const floatx4* p1 = (const floatx4*)(cls + (size_t)(base + 1) * C_DIM);
    s.q00 = __builtin_nontemporal_load(p0 + lane);
    s.q10 = __builtin_nontemporal_load(p1 + lane);
    s.q01 = __builtin_nontemporal_load(p0 + v1);
    s.q11 = __builtin_nontemporal_load(p1 + v1);
    const int rw = base + lidx;
    s.a = *(const floatx4*)(anchors + (size_t)(rw % N_DIM) * 4);
    s.r = *(const floatx4*)(reg + (size_t)rw * 4);
    return s;
}

__global__ __launch_bounds__(256) void InferenceTransform_66202625900988_kernel(
    const float* __restrict__ cls,       // [B,N,C]
    const float* __restrict__ reg,       // [B,N,4]
    const float* __restrict__ anchors,   // [1,N,4]
    const float* __restrict__ thresh_p,  // [1]
    const float* __restrict__ rfac,      // [4]
    float* __restrict__ out)             // boxes[B*N*4] | cls[B*N] | scores[B*N] | mask[B*N]
{
    const int lane          = threadIdx.x & 63;
    const int waveInBlock   = threadIdx.x >> 6;
    const int wavesPerBlock = blockDim.x >> 6;
    const int nWaves        = gridDim.x * wavesPerBlock;

    // XCD-contiguous remap (MI355X: 8 XCDs, round-robin block dispatch).
    // grid=2048 -> 256 blocks/XCD exactly; bijection on [0, 2048).
    const int xcd    = blockIdx.x & 7;
    const int slot   = blockIdx.x >> 3;
    const int waveId = (xcd * (gridDim.x >> 3) + slot) * wavesPerBlock + waveInBlock;

    const int v1   = (lane + 64 < C_DIM / 4) ? (lane + 64) : (C_DIM / 4 - 1);
    const int lidx = (lane < 2) ? lane : 1;   // lanes >=2 replicate lane 1

    const float thresh = thresh_p[0];
    const float rf0 = rfac[0], rf1 = rfac[1], rf2 = rfac[2], rf3 = rfac[3];

    float*       outBoxes = out;
    float*       outCls   = out + (size_t)TOTAL_ROWS * 4;
    float*       outScore = outCls + (size_t)TOTAL_ROWS;
    float*       outMask  = outScore + (size_t)TOTAL_ROWS;

    int batch = waveId;   // 8192 waves <= 200000 batches: all waves have work
    Stage cur = load_stage(cls, anchors, reg, batch, lane, v1, lidx);

    while (true) {
        const int nb = batch + nWaves;
        // Clamped (never branched) prefetch: final iteration prefetches batch
        // 0 -- all waves share those 4 KB, caches absorb it.
        const int pb = (nb < NBATCH) ? nb : 0;
        Stage nxt = load_stage(cls, anchors, reg, pb, lane, v1, lidx);

        // ---- process current batch (rows base, base+1) ----
        const int base = batch * 2;
        float loc0 = -1.0f, loc1 = -1.0f;
        int   bidx0 = 0,    bidx1 = 0;
        scan4(cur.q00, 4 * lane, loc0, bidx0);
        scan4(cur.q10, 4 * lane, loc1, bidx1);
        scan4(cur.q01, 4 * v1,   loc0, bidx0);   // dup lanes carry true idx
        scan4(cur.q11, 4 * v1,   loc1, bidx1);

        float w0 = loc0, w1 = loc1;
        #pragma unroll
        for (int off = 32; off > 0; off >>= 1) {
            w0 = fmaxf(w0, __shfl_xor(w0, off, 64));
            w1 = fmaxf(w1, __shfl_xor(w1, off, 64));
        }

        // Argmax: prefer chunk-0 (idx<256) candidates; idx monotone (non-
        // decreasing) in lane within a chunk -> lowest set lane = first idx.
        unsigned long long c0a = __ballot(loc0 == w0 && bidx0 < 256);
        unsigned long long c0  = c0a ? c0a : __ballot(loc0 == w0);
        unsigned long long c1a = __ballot(loc1 == w1 && bidx1 < 256);
        unsigned long long c1  = c1a ? c1a : __ballot(loc1 == w1);
        int idx0 = __shfl(bidx0, (int)__builtin_ctzll(c0), 64);
        int idx1 = __shfl(bidx1, (int)__builtin_ctzll(c1), 64);

        // ---- epilogue on ALL lanes (lanes>=2 exactly replicate lane 1;
        // duplicate-address stores coalesce) ----
        {
            const int   row  = base + lidx;
            const float best = lidx ? w1 : w0;
            const int   bidx = lidx ? idx1 : idx0;

            float width  = cur.a.z - cur.a.x;
            float height = cur.a.w - cur.a.y;
            float ctrx   = cur.a.x + 0.5f * width;
            float ctry   = cur.a.y + 0.5f * height;

            float px = ctrx + (cur.r.x * rf0) * width;
            float py = ctry + (cur.r.y * rf1) * height;
            float pw = __expf(cur.r.z * rf2) * width;
            float ph = __expf(cur.r.w * rf3) * height;

            float x1 = fminf(fmaxf(px - 0.5f * pw, 0.0f), IMG_W);
            float y1 = fminf(fmaxf(py - 0.5f * ph, 0.0f), IMG_H);
            float x2 = fminf(fmaxf(px + 0.5f * pw, 0.0f), IMG_W);
            float y2 = fminf(fmaxf(py + 0.5f * ph, 0.0f), IMG_H);

            const float m = (best > thresh) ? 1.0f : 0.0f;

            floatx4 box;
            box.x = x1 * m; box.y = y1 * m; box.z = x2 * m; box.w = y2 * m;
            *(floatx4*)(outBoxes + (size_t)row * 4) = box;
            outCls[row]   = m != 0.0f ? (float)bidx : 0.0f;
            outScore[row] = best * m;
            outMask[row]  = m;
        }

        if (nb >= NBATCH) break;
        batch = nb;
        cur = nxt;
    }
}

extern "C" void kernel_launch(void* const* d_in, const int* in_sizes, int n_in,
                              void* d_out, int out_size, void* d_ws, size_t ws_size,
                              hipStream_t stream) {
    // Input order per setup_inputs(): imgs, classifications, regressions,
    // anchors, cls_thresh, regress_factor.
    const float* cls     = (const float*)d_in[1];
    const float* reg     = (const float*)d_in[2];
    const float* anchors = (const float*)d_in[3];
    const float* thresh  = (const float*)d_in[4];
    const float* rfac    = (const float*)d_in[5];
    float* out = (float*)d_out;

    const int block = 256;   // 4 waves/block
    const int grid  = 2048;  // 8192 waves; 256 blocks per XCD (exact)

    InferenceTransform_66202625900988_kernel<<<grid, block, 0, stream>>>(
        cls, reg, anchors, thresh, rfac, out);
}